// Round 14
// baseline (200.174 us; speedup 1.0000x reference)
//
#include <hip/hip_runtime.h>
#include <hip/hip_fp16.h>

// 2-layer GCN, pull-based CSR aggregation. fp32 math; h1 fp8-e4m3 (halves
// agg1 gather traffic), z/h2 fp16 (absmax is fp16 ulp -> h2 stays fp16).
// CSR build with ZERO global atomics (R5/R6: device atomics cap ~6/cyc).
// gemm1 = MFMA f16; fp8 epilogue via stride-132 fp32 LDS tile (R10 fix).
// gemm2 = MFMA f16 (z already fp16; W2 fp16 transposed; 40->48 cols).
// agg1 = 2 waves per node (R13: latency-bound at 8 gathers/wave in flight;
// edge-split across wave pair doubles MLP without R12's register/tier cost).

#define FDIM 128
#define CHUNK 2048   // edges per chunk; nchunks = ceil(E/CHUNK) must be <= 512

using half8   = __attribute__((ext_vector_type(8))) _Float16;
using float4v = __attribute__((ext_vector_type(4))) float;
using float2v = __attribute__((ext_vector_type(2))) float;

__device__ __forceinline__ float2v fp8x2_to_f32x2(unsigned short hv) {
    return __builtin_amdgcn_cvt_pk_f32_fp8((int)hv, false);
}

__global__ void hist_kernel(const int* __restrict__ dst, int E, int nchunks, int nbk,
                            int* __restrict__ histT) {
    __shared__ int hist[256];
    int j = blockIdx.x, t = threadIdx.x;
    hist[t] = 0;
    __syncthreads();
    int base = j * CHUNK;
#pragma unroll
    for (int k = 0; k < CHUNK / 256; ++k) {
        int e = base + k * 256 + t;
        if (e < E) atomicAdd(&hist[dst[e] >> 8], 1);
    }
    __syncthreads();
    if (t < nbk) histT[t * nchunks + j] = hist[t];
}

// per-bucket: exclusive scan of chunk counts (LOCAL), bucket total out
__global__ void offsets_kernel(int* __restrict__ histT, int nchunks,
                               int* __restrict__ tot) {
    __shared__ int s[512];
    int b = blockIdx.x, t = threadIdx.x;
    int* row = histT + (size_t)b * nchunks;
    int v = (t < nchunks) ? row[t] : 0;
    s[t] = v;
    __syncthreads();
    for (int off = 1; off < 512; off <<= 1) {
        int tv = (t >= off) ? s[t - off] : 0;
        __syncthreads();
        s[t] += tv;
        __syncthreads();
    }
    if (t < nchunks) row[t] = s[t] - v;     // local exclusive offset
    if (t == 511) tot[b] = s[511];          // bucket total
}

__global__ void scatter_kernel(const int* __restrict__ ei, int E, int nchunks, int nbk,
                               const int* __restrict__ histT, const int* __restrict__ tot,
                               unsigned* __restrict__ bkt) {
    __shared__ int s[256];
    __shared__ int cur[256];
    int j = blockIdx.x, t = threadIdx.x;
    int v = (t < nbk) ? tot[t] : 0;
    s[t] = v;
    __syncthreads();
    for (int off = 1; off < 256; off <<= 1) {
        int tv = (t >= off) ? s[t - off] : 0;
        __syncthreads();
        s[t] += tv;
        __syncthreads();
    }
    if (t < nbk) cur[t] = (s[t] - v) + histT[t * nchunks + j];
    __syncthreads();
    int base = j * CHUNK;
#pragma unroll
    for (int k = 0; k < CHUNK / 256; ++k) {
        int e = base + k * 256 + t;
        if (e < E) {
            int src = ei[e];
            int d = ei[E + e];
            int pos = atomicAdd(&cur[d >> 8], 1);   // LDS atomic
            bkt[pos] = ((unsigned)(d & 255) << 24) | (unsigned)src;
        }
    }
}

__global__ void csr_kernel(const int* __restrict__ tot, const unsigned* __restrict__ bkt,
                           int* __restrict__ adj, int* __restrict__ rowstart,
                           float* __restrict__ dinv, int N, int nbk, int E) {
    __shared__ int sbuf[256];
    __shared__ int hist[256];
    __shared__ int cur[256];
    int b = blockIdx.x, t = threadIdx.x;
    int v = (t < nbk) ? tot[t] : 0;
    sbuf[t] = v;
    __syncthreads();
    for (int off = 1; off < 256; off <<= 1) {
        int tv = (t >= off) ? sbuf[t - off] : 0;
        __syncthreads();
        sbuf[t] += tv;
        __syncthreads();
    }
    int bb = sbuf[b] - ((b < nbk) ? tot[b] : 0);
    int nb = tot[b];
    __syncthreads();
    hist[t] = 0;
    __syncthreads();
    const unsigned* bk = bkt + bb;
    for (int e = t; e < nb; e += 256) atomicAdd(&hist[bk[e] >> 24], 1);
    __syncthreads();
    int h_t = hist[t];
    sbuf[t] = h_t;
    __syncthreads();
    for (int off = 1; off < 256; off <<= 1) {
        int vv = (t >= off) ? sbuf[t - off] : 0;
        __syncthreads();
        sbuf[t] += vv;
        __syncthreads();
    }
    int excl_t = sbuf[t] - h_t;
    int node = b * 256 + t;
    if (node < N) {
        rowstart[node] = bb + excl_t;
        dinv[node] = rsqrtf((float)(h_t + 1));   // +1 self-loop
    }
    if (b == 0 && t == 0) rowstart[N] = E;
    cur[t] = excl_t;
    __syncthreads();
    for (int e = t; e < nb; e += 256) {
        unsigned vv = bk[e];
        int pos = atomicAdd(&cur[vv >> 24], 1);   // LDS atomic
        adj[bb + pos] = (int)(vv & 0xFFFFFFu);    // src < 2^24
    }
}

// ---- MFMA GEMM1: h1 = fp16(x) @ fp16(W1), fp32 accum, fp8-e4m3 out ----
__launch_bounds__(256, 2)
__global__ void gemm1_mfma(const float* __restrict__ x, const float* __restrict__ W,
                           unsigned char* __restrict__ h, int N) {
    __shared__ __align__(16) unsigned char smem[69632];
    _Float16* Xs = (_Float16*)smem;
    _Float16* Wt = (_Float16*)(smem + 34816);
    int t = threadIdx.x;
    int i0 = blockIdx.x * 128;

    for (int p = t; p < 128 * 32; p += 256) {
        int row = p >> 5;
        int col4 = (p & 31) * 4;
        int grow = i0 + row;
        float4 v = make_float4(0.f, 0.f, 0.f, 0.f);
        if (grow < N) v = *(const float4*)(x + (size_t)grow * FDIM + col4);
        _Float16* d = &Xs[row * 136 + col4];
        d[0] = (_Float16)v.x;
        d[1] = (_Float16)v.y;
        d[2] = (_Float16)v.z;
        d[3] = (_Float16)v.w;
    }
    for (int p = t; p < 128 * 128; p += 256) {
        int k = p >> 7;
        int n = p & 127;
        Wt[n * 136 + k] = (_Float16)W[k * 128 + n];
    }
    __syncthreads();

    int lane = t & 63, w = t >> 6;
    int c = lane & 15, q = lane >> 4;
    int m0 = w * 32;

    float4v acc[2][8];
#pragma unroll
    for (int r = 0; r < 2; ++r)
#pragma unroll
        for (int nt = 0; nt < 8; ++nt) acc[r][nt] = (float4v)(0.f);

#pragma unroll
    for (int kk = 0; kk < 4; ++kk) {
        int k0 = kk * 32 + q * 8;
        half8 a0 = *(const half8*)&Xs[(m0 + c) * 136 + k0];
        half8 a1 = *(const half8*)&Xs[(m0 + 16 + c) * 136 + k0];
#pragma unroll
        for (int nt = 0; nt < 8; ++nt) {
            half8 bv = *(const half8*)&Wt[(nt * 16 + c) * 136 + k0];
            acc[0][nt] = __builtin_amdgcn_mfma_f32_16x16x32_f16(a0, bv, acc[0][nt], 0, 0, 0);
            acc[1][nt] = __builtin_amdgcn_mfma_f32_16x16x32_f16(a1, bv, acc[1][nt], 0, 0, 0);
        }
    }
    __syncthreads();   // staging dead; reuse smem as fp32 tile T[128][132]
    float* T = (float*)smem;
#pragma unroll
    for (int r = 0; r < 2; ++r)
#pragma unroll
        for (int reg = 0; reg < 4; ++reg) {
            int rl = m0 + r * 16 + q * 4 + reg;
#pragma unroll
            for (int nt = 0; nt < 8; ++nt)
                T[rl * 132 + nt * 16 + c] = acc[r][nt][reg];
        }
    __syncthreads();
    for (int p = t; p < 128 * 32; p += 256) {
        int row = p >> 5;
        int col4 = (p & 31) * 4;
        int grow = i0 + row;
        if (grow < N) {
            const float* src = &T[row * 132 + col4];
            int lo = __builtin_amdgcn_cvt_pk_fp8_f32(src[0], src[1], 0, false);
            int hi = __builtin_amdgcn_cvt_pk_fp8_f32(src[2], src[3], 0, false);
            unsigned word = ((unsigned)lo & 0xFFFFu) | (((unsigned)hi & 0xFFFFu) << 16);
            *(unsigned*)(h + (size_t)grow * 128 + col4) = word;
        }
    }
}

// z[i,:] = relu( dinv[i]*(sum_s h1[s,:]*dinv[s] + h1[i,:]*dinv[i]) + b1 ) + x[i,:]
// h1 fp8-e4m3, 128 B/row. TWO waves per node: each runs the 8/4/1 tier
// pipeline on half the row (16 gathers in flight per node), partials
// combined through LDS with one barrier.
__global__ void agg1_kernel(const unsigned char* __restrict__ h1, const int* __restrict__ rowstart,
                            const int* __restrict__ adj, const float* __restrict__ dinv,
                            const float* __restrict__ x, const float* __restrict__ b1,
                            __half* __restrict__ z, int N) {
    __shared__ float part[2][2][64];
    int wave = threadIdx.x >> 6;          // 0..3
    int lane = threadIdx.x & 63;
    int slot = wave >> 1;                 // node slot in block
    int half = wave & 1;
    int i = blockIdx.x * 2 + slot;
    bool alive = (i < N);
    int s0 = 0, s1 = 0;
    if (alive) { s0 = rowstart[i]; s1 = rowstart[i + 1]; }
    int cnt = s1 - s0;
    int c0 = cnt >> 1;
    int nb = s0 + half * c0;              // this wave's begin
    int ne = half ? s1 : (s0 + c0);       // this wave's end
    float ax = 0.f, ay = 0.f;
    int n = nb;
    for (; n + 7 < ne; n += 8) {
        int s[8];
        float w[8];
        unsigned short hv[8];
#pragma unroll
        for (int q = 0; q < 8; ++q) s[q] = adj[n + q];
#pragma unroll
        for (int q = 0; q < 8; ++q) w[q] = dinv[s[q]];
#pragma unroll
        for (int q = 0; q < 8; ++q)
            hv[q] = *(const unsigned short*)(h1 + (size_t)s[q] * 128 + lane * 2);
#pragma unroll
        for (int q = 0; q < 8; ++q) {
            float2v f = fp8x2_to_f32x2(hv[q]);
            ax += f.x * w[q];
            ay += f.y * w[q];
        }
    }
    if (n + 3 < ne) {
        int s[4];
        float w[4];
        unsigned short hv[4];
#pragma unroll
        for (int q = 0; q < 4; ++q) s[q] = adj[n + q];
#pragma unroll
        for (int q = 0; q < 4; ++q) w[q] = dinv[s[q]];
#pragma unroll
        for (int q = 0; q < 4; ++q)
            hv[q] = *(const unsigned short*)(h1 + (size_t)s[q] * 128 + lane * 2);
#pragma unroll
        for (int q = 0; q < 4; ++q) {
            float2v f = fp8x2_to_f32x2(hv[q]);
            ax += f.x * w[q];
            ay += f.y * w[q];
        }
        n += 4;
    }
    for (; n < ne; ++n) {
        int sa = adj[n];
        float wa = dinv[sa];
        float2v f = fp8x2_to_f32x2(*(const unsigned short*)(h1 + (size_t)sa * 128 + lane * 2));
        ax += f.x * wa;
        ay += f.y * wa;
    }
    if (half) {
        part[slot][0][lane] = ax;
        part[slot][1][lane] = ay;
    }
    __syncthreads();
    if (!half && alive) {
        ax += part[slot][0][lane];
        ay += part[slot][1][lane];
        float di = dinv[i];
        float self = di * di;
        float2v hi = fp8x2_to_f32x2(*(const unsigned short*)(h1 + (size_t)i * 128 + lane * 2));
        ax = ax * di + hi.x * self;
        ay = ay * di + hi.y * self;
        float2 bb = ((const float2*)b1)[lane];
        float2 xi = ((const float2*)(x + (size_t)i * FDIM))[lane];
        float rx = fmaxf(ax + bb.x, 0.f) + xi.x;
        float ry = fmaxf(ay + bb.y, 0.f) + xi.y;
        ((__half2*)(z + (size_t)i * FDIM))[lane] = __floats2half2_rn(rx, ry);
    }
}

// ---- MFMA GEMM2: h2 = z @ fp16(W2), fp32 accum, fp16 out (stride 40) ----
__launch_bounds__(256, 2)
__global__ void gemm2_mfma(const __half* __restrict__ z, const float* __restrict__ W2,
                           __half* __restrict__ h2, int N) {
    __shared__ __align__(16) unsigned char smem[49152];
    _Float16* Zs  = (_Float16*)smem;                 // 128*136*2 = 34816 B
    _Float16* W2t = (_Float16*)(smem + 34816);       // 48*136*2  = 13056 B
    int t = threadIdx.x;
    int i0 = blockIdx.x * 128;

    for (int p = t; p < 128 * 16; p += 256) {
        int row = p >> 4;
        int ck = (p & 15) * 8;
        int grow = i0 + row;
        half8 v = (half8)(_Float16)0;
        if (grow < N) v = *(const half8*)(z + (size_t)grow * FDIM + ck);
        *(half8*)&Zs[row * 136 + ck] = v;
    }
    for (int p = t; p < 48 * 128; p += 256) {
        int n = p >> 7;
        int k = p & 127;
        W2t[n * 136 + k] = (n < 40) ? (_Float16)W2[k * 40 + n] : (_Float16)0;
    }
    __syncthreads();

    int lane = t & 63, w = t >> 6;
    int c = lane & 15, q = lane >> 4;
    int m0 = w * 32;

    float4v acc[2][3];
#pragma unroll
    for (int r = 0; r < 2; ++r)
#pragma unroll
        for (int nt = 0; nt < 3; ++nt) acc[r][nt] = (float4v)(0.f);

#pragma unroll
    for (int kk = 0; kk < 4; ++kk) {
        int k0 = kk * 32 + q * 8;
        half8 a0 = *(const half8*)&Zs[(m0 + c) * 136 + k0];
        half8 a1 = *(const half8*)&Zs[(m0 + 16 + c) * 136 + k0];
#pragma unroll
        for (int nt = 0; nt < 3; ++nt) {
            half8 bv = *(const half8*)&W2t[(nt * 16 + c) * 136 + k0];
            acc[0][nt] = __builtin_amdgcn_mfma_f32_16x16x32_f16(a0, bv, acc[0][nt], 0, 0, 0);
            acc[1][nt] = __builtin_amdgcn_mfma_f32_16x16x32_f16(a1, bv, acc[1][nt], 0, 0, 0);
        }
    }
    __syncthreads();   // Zs/W2t dead; reuse smem as fp16 tile T[128][58]
    _Float16* T = (_Float16*)smem;
#pragma unroll
    for (int r = 0; r < 2; ++r)
#pragma unroll
        for (int reg = 0; reg < 4; ++reg) {
            int rl = m0 + r * 16 + q * 4 + reg;
#pragma unroll
            for (int nt = 0; nt < 3; ++nt)
                T[rl * 58 + nt * 16 + c] = (_Float16)acc[r][nt][reg];
        }
    __syncthreads();
    for (int p = t; p < 128 * 20; p += 256) {
        int row = p / 20;
        int c2 = p % 20;
        int grow = i0 + row;
        if (grow < N)
            *(__half2*)(h2 + (size_t)grow * 40 + c2 * 2) =
                *(const __half2*)&T[row * 58 + c2 * 2];
    }
}

// y[i,:] = dinv[i]*(sum_s h2[s,:]*dinv[s] + h2[i,:]*dinv[i]) + b2
__global__ void agg2_kernel(const __half* __restrict__ h2, const int* __restrict__ rowstart,
                            const int* __restrict__ adj, const float* __restrict__ dinv,
                            const float* __restrict__ b2, float* __restrict__ y, int N) {
    int wave = threadIdx.x >> 6;
    int lane = threadIdx.x & 63;
    int i = blockIdx.x * 4 + wave;
    if (i >= N) return;
    int e = (lane >= 40) ? 2 : ((lane >= 20) ? 1 : 0);
    int f = lane - 20 * e;
    int s0 = rowstart[i], s1 = rowstart[i + 1];
    float ax = 0.f, ay = 0.f;
    if (lane < 60) {
        int n = s0 + e;
        for (; n + 9 < s1; n += 12) {
            int s[4];
            float w[4];
            float2 r[4];
#pragma unroll
            for (int q = 0; q < 4; ++q) s[q] = adj[n + 3 * q];
#pragma unroll
            for (int q = 0; q < 4; ++q) w[q] = dinv[s[q]];
#pragma unroll
            for (int q = 0; q < 4; ++q)
                r[q] = __half22float2(((const __half2*)(h2 + (size_t)s[q] * 40))[f]);
#pragma unroll
            for (int q = 0; q < 4; ++q) {
                ax += r[q].x * w[q];
                ay += r[q].y * w[q];
            }
        }
        for (; n < s1; n += 3) {
            int sa = adj[n];
            float wa = dinv[sa];
            float2 ra = __half22float2(((const __half2*)(h2 + (size_t)sa * 40))[f]);
            ax += ra.x * wa;
            ay += ra.y * wa;
        }
    }
    float sx = ax + __shfl(ax, lane + 20, 64) + __shfl(ax, lane + 40, 64);
    float sy = ay + __shfl(ay, lane + 20, 64) + __shfl(ay, lane + 40, 64);
    if (lane < 20) {
        float di = dinv[i];
        float2 hi = __half22float2(((const __half2*)(h2 + (size_t)i * 40))[lane]);
        float2 bb = ((const float2*)b2)[lane];
        float2 res;
        res.x = sx * di + hi.x * di * di + bb.x;
        res.y = sy * di + hi.y * di * di + bb.y;
        ((float2*)(y + (size_t)i * 40))[lane] = res;
    }
}

extern "C" void kernel_launch(void* const* d_in, const int* in_sizes, int n_in,
                              void* d_out, int out_size, void* d_ws, size_t ws_size,
                              hipStream_t stream) {
    const float* x  = (const float*)d_in[0];
    const int*   ei = (const int*)d_in[1];
    const float* W1 = (const float*)d_in[2];
    const float* b1 = (const float*)d_in[3];
    const float* W2 = (const float*)d_in[4];
    const float* b2 = (const float*)d_in[5];
    float* y = (float*)d_out;

    const int H = in_sizes[3];           // 128
    const int F = in_sizes[2] / H;       // 128
    const int N = in_sizes[0] / F;       // 50000
    const int E = in_sizes[1] / 2;       // 800000
    (void)H; (void)ws_size; (void)n_in; (void)out_size;

    const int nbk = (N + 255) >> 8;              // 196 buckets (<=256)
    const int nchunks = (E + CHUNK - 1) / CHUNK; // 391 (<=512)

    size_t off = 0;
    auto carve = [&](size_t bytes) -> void* {
        void* p = (char*)d_ws + off;
        off += (bytes + 255) & ~(size_t)255;
        return p;
    };
    int*           histT    = (int*)carve((size_t)nbk * nchunks * 4);
    int*           tot      = (int*)carve((size_t)nbk * 4);
    unsigned*      bkt      = (unsigned*)carve((size_t)E * 4);
    int*           rowstart = (int*)carve((size_t)(N + 1) * 4);
    float*         dinv     = (float*)carve((size_t)N * 4);
    int*           adj      = (int*)carve((size_t)E * 4);
    unsigned char* h1       = (unsigned char*)carve((size_t)N * 128);   // fp8 e4m3
    __half*        z        = (__half*)carve((size_t)N * FDIM * 2);
    __half*        h2       = (__half*)h1;   // h1 dead after agg1; N x 40 fp16 fits

    hist_kernel<<<nchunks, 256, 0, stream>>>(ei + E, E, nchunks, nbk, histT);
    offsets_kernel<<<nbk, 512, 0, stream>>>(histT, nchunks, tot);
    scatter_kernel<<<nchunks, 256, 0, stream>>>(ei, E, nchunks, nbk, histT, tot, bkt);
    csr_kernel<<<nbk, 256, 0, stream>>>(tot, bkt, adj, rowstart, dinv, N, nbk, E);

    int nbt = (N + 127) / 128;
    gemm1_mfma<<<nbt, 256, 0, stream>>>(x, W1, h1, N);
    agg1_kernel<<<(N + 1) / 2, 256, 0, stream>>>(h1, rowstart, adj, dinv, x, b1, z, N);
    gemm2_mfma<<<nbt, 256, 0, stream>>>(z, W2, h2, N);
    agg2_kernel<<<(N + 3) / 4, 256, 0, stream>>>(h2, rowstart, adj, dinv, b2, y, N);
}

// Round 15
// 189.354 us; speedup vs baseline: 1.0571x; 1.0571x over previous
//
#include <hip/hip_runtime.h>
#include <hip/hip_fp16.h>

// 2-layer GCN, pull-based CSR aggregation. fp32 math; h1 fp8-e4m3, z/h2 fp16.
// CSR build with ZERO global atomics (R5/R6: device atomics cap ~6/cyc).
// R14 post-mortem: agg1 2-wave split regressed (wave-level MLP already
// saturates memory path at 68% occupancy) -> reverted to R13 form.
// R15 change: scatter does an LDS counting-sort per 2048-edge chunk so
// bucket payloads are written in contiguous runs (kills 64B-line write
// amplification measured at 39-52MB on earlier scatter variants).
// gemm1 = MFMA f16 -> fp8 out (stride-132 fp32 LDS epilogue, R10 fix).
// gemm2 = MFMA f16 (W2 fp16 transposed, 40->48 cols).

#define FDIM 128
#define CHUNK 2048   // edges per chunk; nchunks = ceil(E/CHUNK) must be <= 512

using half8   = __attribute__((ext_vector_type(8))) _Float16;
using float4v = __attribute__((ext_vector_type(4))) float;
using float2v = __attribute__((ext_vector_type(2))) float;

__device__ __forceinline__ float2v fp8x2_to_f32x2(unsigned short hv) {
    return __builtin_amdgcn_cvt_pk_f32_fp8((int)hv, false);
}

__global__ void hist_kernel(const int* __restrict__ dst, int E, int nchunks, int nbk,
                            int* __restrict__ histT) {
    __shared__ int hist[256];
    int j = blockIdx.x, t = threadIdx.x;
    hist[t] = 0;
    __syncthreads();
    int base = j * CHUNK;
#pragma unroll
    for (int k = 0; k < CHUNK / 256; ++k) {
        int e = base + k * 256 + t;
        if (e < E) atomicAdd(&hist[dst[e] >> 8], 1);
    }
    __syncthreads();
    if (t < nbk) histT[t * nchunks + j] = hist[t];
}

// per-bucket: exclusive scan of chunk counts (LOCAL), bucket total out
__global__ void offsets_kernel(int* __restrict__ histT, int nchunks,
                               int* __restrict__ tot) {
    __shared__ int s[512];
    int b = blockIdx.x, t = threadIdx.x;
    int* row = histT + (size_t)b * nchunks;
    int v = (t < nchunks) ? row[t] : 0;
    s[t] = v;
    __syncthreads();
    for (int off = 1; off < 512; off <<= 1) {
        int tv = (t >= off) ? s[t - off] : 0;
        __syncthreads();
        s[t] += tv;
        __syncthreads();
    }
    if (t < nchunks) row[t] = s[t] - v;     // local exclusive offset
    if (t == 511) tot[b] = s[511];          // bucket total
}

// scatter with in-LDS counting sort: payloads leave in contiguous bucket runs.
__global__ void scatter_kernel(const int* __restrict__ ei, int E, int nchunks, int nbk,
                               const int* __restrict__ histT, const int* __restrict__ tot,
                               unsigned* __restrict__ bkt) {
    __shared__ int s[256];
    __shared__ int delta[256];    // global_dest = delta[b] + local_pos
    __shared__ int lcur[256];     // local cursor (seeded with local excl offset)
    __shared__ unsigned buf[CHUNK];
    __shared__ int dst32[CHUNK];
    int j = blockIdx.x, t = threadIdx.x;

    // global base of bucket t: exclusive scan of tot
    int v = (t < nbk) ? tot[t] : 0;
    s[t] = v;
    __syncthreads();
    for (int off = 1; off < 256; off <<= 1) {
        int tv = (t >= off) ? s[t - off] : 0;
        __syncthreads();
        s[t] += tv;
        __syncthreads();
    }
    int gbase = (t < nbk) ? (s[t] - v) + histT[t * nchunks + j] : 0;  // global cursor start
    // local chunk count for bucket t (derived from cumulative offsets)
    int lcnt = 0;
    if (t < nbk) {
        int cur_off = histT[t * nchunks + j];
        int nxt_off = (j + 1 < nchunks) ? histT[t * nchunks + j + 1] : tot[t];
        lcnt = nxt_off - cur_off;
    }
    __syncthreads();
    // local exclusive scan of lcnt
    s[t] = lcnt;
    __syncthreads();
    for (int off = 1; off < 256; off <<= 1) {
        int tv = (t >= off) ? s[t - off] : 0;
        __syncthreads();
        s[t] += tv;
        __syncthreads();
    }
    int lofs = s[t] - lcnt;
    lcur[t] = lofs;
    delta[t] = gbase - lofs;
    __syncthreads();

    // pass 1: sort payloads into buf by bucket; record global dest
    int base = j * CHUNK;
#pragma unroll
    for (int k = 0; k < CHUNK / 256; ++k) {
        int e = base + k * 256 + t;
        if (e < E) {
            int src = ei[e];
            int d = ei[E + e];
            int b = d >> 8;
            int pos = atomicAdd(&lcur[b], 1);   // LDS atomic
            buf[pos] = ((unsigned)(d & 255) << 24) | (unsigned)src;
            dst32[pos] = delta[b] + pos;
        }
    }
    __syncthreads();
    // pass 2: write out; consecutive p within a bucket run -> contiguous dest
    int cnt = min(CHUNK, E - base);
    for (int p = t; p < cnt; p += 256)
        bkt[dst32[p]] = buf[p];
}

__global__ void csr_kernel(const int* __restrict__ tot, const unsigned* __restrict__ bkt,
                           int* __restrict__ adj, int* __restrict__ rowstart,
                           float* __restrict__ dinv, int N, int nbk, int E) {
    __shared__ int sbuf[256];
    __shared__ int hist[256];
    __shared__ int cur[256];
    int b = blockIdx.x, t = threadIdx.x;
    int v = (t < nbk) ? tot[t] : 0;
    sbuf[t] = v;
    __syncthreads();
    for (int off = 1; off < 256; off <<= 1) {
        int tv = (t >= off) ? sbuf[t - off] : 0;
        __syncthreads();
        sbuf[t] += tv;
        __syncthreads();
    }
    int bb = sbuf[b] - ((b < nbk) ? tot[b] : 0);
    int nb = tot[b];
    __syncthreads();
    hist[t] = 0;
    __syncthreads();
    const unsigned* bk = bkt + bb;
    for (int e = t; e < nb; e += 256) atomicAdd(&hist[bk[e] >> 24], 1);
    __syncthreads();
    int h_t = hist[t];
    sbuf[t] = h_t;
    __syncthreads();
    for (int off = 1; off < 256; off <<= 1) {
        int vv = (t >= off) ? sbuf[t - off] : 0;
        __syncthreads();
        sbuf[t] += vv;
        __syncthreads();
    }
    int excl_t = sbuf[t] - h_t;
    int node = b * 256 + t;
    if (node < N) {
        rowstart[node] = bb + excl_t;
        dinv[node] = rsqrtf((float)(h_t + 1));   // +1 self-loop
    }
    if (b == 0 && t == 0) rowstart[N] = E;
    cur[t] = excl_t;
    __syncthreads();
    for (int e = t; e < nb; e += 256) {
        unsigned vv = bk[e];
        int pos = atomicAdd(&cur[vv >> 24], 1);   // LDS atomic
        adj[bb + pos] = (int)(vv & 0xFFFFFFu);    // src < 2^24
    }
}

// ---- MFMA GEMM1: h1 = fp16(x) @ fp16(W1), fp32 accum, fp8-e4m3 out ----
__launch_bounds__(256, 2)
__global__ void gemm1_mfma(const float* __restrict__ x, const float* __restrict__ W,
                           unsigned char* __restrict__ h, int N) {
    __shared__ __align__(16) unsigned char smem[69632];
    _Float16* Xs = (_Float16*)smem;
    _Float16* Wt = (_Float16*)(smem + 34816);
    int t = threadIdx.x;
    int i0 = blockIdx.x * 128;

    for (int p = t; p < 128 * 32; p += 256) {
        int row = p >> 5;
        int col4 = (p & 31) * 4;
        int grow = i0 + row;
        float4 v = make_float4(0.f, 0.f, 0.f, 0.f);
        if (grow < N) v = *(const float4*)(x + (size_t)grow * FDIM + col4);
        _Float16* d = &Xs[row * 136 + col4];
        d[0] = (_Float16)v.x;
        d[1] = (_Float16)v.y;
        d[2] = (_Float16)v.z;
        d[3] = (_Float16)v.w;
    }
    for (int p = t; p < 128 * 128; p += 256) {
        int k = p >> 7;
        int n = p & 127;
        Wt[n * 136 + k] = (_Float16)W[k * 128 + n];
    }
    __syncthreads();

    int lane = t & 63, w = t >> 6;
    int c = lane & 15, q = lane >> 4;
    int m0 = w * 32;

    float4v acc[2][8];
#pragma unroll
    for (int r = 0; r < 2; ++r)
#pragma unroll
        for (int nt = 0; nt < 8; ++nt) acc[r][nt] = (float4v)(0.f);

#pragma unroll
    for (int kk = 0; kk < 4; ++kk) {
        int k0 = kk * 32 + q * 8;
        half8 a0 = *(const half8*)&Xs[(m0 + c) * 136 + k0];
        half8 a1 = *(const half8*)&Xs[(m0 + 16 + c) * 136 + k0];
#pragma unroll
        for (int nt = 0; nt < 8; ++nt) {
            half8 bv = *(const half8*)&Wt[(nt * 16 + c) * 136 + k0];
            acc[0][nt] = __builtin_amdgcn_mfma_f32_16x16x32_f16(a0, bv, acc[0][nt], 0, 0, 0);
            acc[1][nt] = __builtin_amdgcn_mfma_f32_16x16x32_f16(a1, bv, acc[1][nt], 0, 0, 0);
        }
    }
    __syncthreads();   // staging dead; reuse smem as fp32 tile T[128][132]
    float* T = (float*)smem;
#pragma unroll
    for (int r = 0; r < 2; ++r)
#pragma unroll
        for (int reg = 0; reg < 4; ++reg) {
            int rl = m0 + r * 16 + q * 4 + reg;
#pragma unroll
            for (int nt = 0; nt < 8; ++nt)
                T[rl * 132 + nt * 16 + c] = acc[r][nt][reg];
        }
    __syncthreads();
    for (int p = t; p < 128 * 32; p += 256) {
        int row = p >> 5;
        int col4 = (p & 31) * 4;
        int grow = i0 + row;
        if (grow < N) {
            const float* src = &T[row * 132 + col4];
            int lo = __builtin_amdgcn_cvt_pk_fp8_f32(src[0], src[1], 0, false);
            int hi = __builtin_amdgcn_cvt_pk_fp8_f32(src[2], src[3], 0, false);
            unsigned word = ((unsigned)lo & 0xFFFFu) | (((unsigned)hi & 0xFFFFu) << 16);
            *(unsigned*)(h + (size_t)grow * 128 + col4) = word;
        }
    }
}

// z[i,:] = relu( dinv[i]*(sum_s h1[s,:]*dinv[s] + h1[i,:]*dinv[i]) + b1 ) + x[i,:]
// h1 fp8-e4m3, 128 B/row; lane = 2 feats; 8 gathers in flight. (R13 form.)
__global__ void agg1_kernel(const unsigned char* __restrict__ h1, const int* __restrict__ rowstart,
                            const int* __restrict__ adj, const float* __restrict__ dinv,
                            const float* __restrict__ x, const float* __restrict__ b1,
                            __half* __restrict__ z, int N) {
    int wave = threadIdx.x >> 6;
    int lane = threadIdx.x & 63;
    int i = blockIdx.x * 4 + wave;
    if (i >= N) return;
    int s0 = rowstart[i], s1 = rowstart[i + 1];
    float ax = 0.f, ay = 0.f;
    int n = s0;
    for (; n + 7 < s1; n += 8) {
        int s[8];
        float w[8];
        unsigned short hv[8];
#pragma unroll
        for (int q = 0; q < 8; ++q) s[q] = adj[n + q];
#pragma unroll
        for (int q = 0; q < 8; ++q) w[q] = dinv[s[q]];
#pragma unroll
        for (int q = 0; q < 8; ++q)
            hv[q] = *(const unsigned short*)(h1 + (size_t)s[q] * 128 + lane * 2);
#pragma unroll
        for (int q = 0; q < 8; ++q) {
            float2v f = fp8x2_to_f32x2(hv[q]);
            ax += f.x * w[q];
            ay += f.y * w[q];
        }
    }
    if (n + 3 < s1) {
        int s[4];
        float w[4];
        unsigned short hv[4];
#pragma unroll
        for (int q = 0; q < 4; ++q) s[q] = adj[n + q];
#pragma unroll
        for (int q = 0; q < 4; ++q) w[q] = dinv[s[q]];
#pragma unroll
        for (int q = 0; q < 4; ++q)
            hv[q] = *(const unsigned short*)(h1 + (size_t)s[q] * 128 + lane * 2);
#pragma unroll
        for (int q = 0; q < 4; ++q) {
            float2v f = fp8x2_to_f32x2(hv[q]);
            ax += f.x * w[q];
            ay += f.y * w[q];
        }
        n += 4;
    }
    for (; n < s1; ++n) {
        int sa = adj[n];
        float wa = dinv[sa];
        float2v f = fp8x2_to_f32x2(*(const unsigned short*)(h1 + (size_t)sa * 128 + lane * 2));
        ax += f.x * wa;
        ay += f.y * wa;
    }
    float di = dinv[i];
    float self = di * di;
    float2v hi = fp8x2_to_f32x2(*(const unsigned short*)(h1 + (size_t)i * 128 + lane * 2));
    ax = ax * di + hi.x * self;
    ay = ay * di + hi.y * self;
    float2 bb = ((const float2*)b1)[lane];
    float2 xi = ((const float2*)(x + (size_t)i * FDIM))[lane];
    float rx = fmaxf(ax + bb.x, 0.f) + xi.x;
    float ry = fmaxf(ay + bb.y, 0.f) + xi.y;
    ((__half2*)(z + (size_t)i * FDIM))[lane] = __floats2half2_rn(rx, ry);
}

// ---- MFMA GEMM2: h2 = z @ fp16(W2), fp32 accum, fp16 out (stride 40) ----
__launch_bounds__(256, 2)
__global__ void gemm2_mfma(const __half* __restrict__ z, const float* __restrict__ W2,
                           __half* __restrict__ h2, int N) {
    __shared__ __align__(16) unsigned char smem[49152];
    _Float16* Zs  = (_Float16*)smem;                 // 128*136*2 = 34816 B
    _Float16* W2t = (_Float16*)(smem + 34816);       // 48*136*2  = 13056 B
    int t = threadIdx.x;
    int i0 = blockIdx.x * 128;

    for (int p = t; p < 128 * 16; p += 256) {
        int row = p >> 4;
        int ck = (p & 15) * 8;
        int grow = i0 + row;
        half8 v = (half8)(_Float16)0;
        if (grow < N) v = *(const half8*)(z + (size_t)grow * FDIM + ck);
        *(half8*)&Zs[row * 136 + ck] = v;
    }
    for (int p = t; p < 48 * 128; p += 256) {
        int n = p >> 7;
        int k = p & 127;
        W2t[n * 136 + k] = (n < 40) ? (_Float16)W2[k * 40 + n] : (_Float16)0;
    }
    __syncthreads();

    int lane = t & 63, w = t >> 6;
    int c = lane & 15, q = lane >> 4;
    int m0 = w * 32;

    float4v acc[2][3];
#pragma unroll
    for (int r = 0; r < 2; ++r)
#pragma unroll
        for (int nt = 0; nt < 3; ++nt) acc[r][nt] = (float4v)(0.f);

#pragma unroll
    for (int kk = 0; kk < 4; ++kk) {
        int k0 = kk * 32 + q * 8;
        half8 a0 = *(const half8*)&Zs[(m0 + c) * 136 + k0];
        half8 a1 = *(const half8*)&Zs[(m0 + 16 + c) * 136 + k0];
#pragma unroll
        for (int nt = 0; nt < 3; ++nt) {
            half8 bv = *(const half8*)&W2t[(nt * 16 + c) * 136 + k0];
            acc[0][nt] = __builtin_amdgcn_mfma_f32_16x16x32_f16(a0, bv, acc[0][nt], 0, 0, 0);
            acc[1][nt] = __builtin_amdgcn_mfma_f32_16x16x32_f16(a1, bv, acc[1][nt], 0, 0, 0);
        }
    }
    __syncthreads();   // Zs/W2t dead; reuse smem as fp16 tile T[128][58]
    _Float16* T = (_Float16*)smem;
#pragma unroll
    for (int r = 0; r < 2; ++r)
#pragma unroll
        for (int reg = 0; reg < 4; ++reg) {
            int rl = m0 + r * 16 + q * 4 + reg;
#pragma unroll
            for (int nt = 0; nt < 3; ++nt)
                T[rl * 58 + nt * 16 + c] = (_Float16)acc[r][nt][reg];
        }
    __syncthreads();
    for (int p = t; p < 128 * 20; p += 256) {
        int row = p / 20;
        int c2 = p % 20;
        int grow = i0 + row;
        if (grow < N)
            *(__half2*)(h2 + (size_t)grow * 40 + c2 * 2) =
                *(const __half2*)&T[row * 58 + c2 * 2];
    }
}

// y[i,:] = dinv[i]*(sum_s h2[s,:]*dinv[s] + h2[i,:]*dinv[i]) + b2
__global__ void agg2_kernel(const __half* __restrict__ h2, const int* __restrict__ rowstart,
                            const int* __restrict__ adj, const float* __restrict__ dinv,
                            const float* __restrict__ b2, float* __restrict__ y, int N) {
    int wave = threadIdx.x >> 6;
    int lane = threadIdx.x & 63;
    int i = blockIdx.x * 4 + wave;
    if (i >= N) return;
    int e = (lane >= 40) ? 2 : ((lane >= 20) ? 1 : 0);
    int f = lane - 20 * e;
    int s0 = rowstart[i], s1 = rowstart[i + 1];
    float ax = 0.f, ay = 0.f;
    if (lane < 60) {
        int n = s0 + e;
        for (; n + 9 < s1; n += 12) {
            int s[4];
            float w[4];
            float2 r[4];
#pragma unroll
            for (int q = 0; q < 4; ++q) s[q] = adj[n + 3 * q];
#pragma unroll
            for (int q = 0; q < 4; ++q) w[q] = dinv[s[q]];
#pragma unroll
            for (int q = 0; q < 4; ++q)
                r[q] = __half22float2(((const __half2*)(h2 + (size_t)s[q] * 40))[f]);
#pragma unroll
            for (int q = 0; q < 4; ++q) {
                ax += r[q].x * w[q];
                ay += r[q].y * w[q];
            }
        }
        for (; n < s1; n += 3) {
            int sa = adj[n];
            float wa = dinv[sa];
            float2 ra = __half22float2(((const __half2*)(h2 + (size_t)sa * 40))[f]);
            ax += ra.x * wa;
            ay += ra.y * wa;
        }
    }
    float sx = ax + __shfl(ax, lane + 20, 64) + __shfl(ax, lane + 40, 64);
    float sy = ay + __shfl(ay, lane + 20, 64) + __shfl(ay, lane + 40, 64);
    if (lane < 20) {
        float di = dinv[i];
        float2 hi = __half22float2(((const __half2*)(h2 + (size_t)i * 40))[lane]);
        float2 bb = ((const float2*)b2)[lane];
        float2 res;
        res.x = sx * di + hi.x * di * di + bb.x;
        res.y = sy * di + hi.y * di * di + bb.y;
        ((float2*)(y + (size_t)i * 40))[lane] = res;
    }
}

extern "C" void kernel_launch(void* const* d_in, const int* in_sizes, int n_in,
                              void* d_out, int out_size, void* d_ws, size_t ws_size,
                              hipStream_t stream) {
    const float* x  = (const float*)d_in[0];
    const int*   ei = (const int*)d_in[1];
    const float* W1 = (const float*)d_in[2];
    const float* b1 = (const float*)d_in[3];
    const float* W2 = (const float*)d_in[4];
    const float* b2 = (const float*)d_in[5];
    float* y = (float*)d_out;

    const int H = in_sizes[3];           // 128
    const int F = in_sizes[2] / H;       // 128
    const int N = in_sizes[0] / F;       // 50000
    const int E = in_sizes[1] / 2;       // 800000
    (void)H; (void)ws_size; (void)n_in; (void)out_size;

    const int nbk = (N + 255) >> 8;              // 196 buckets (<=256)
    const int nchunks = (E + CHUNK - 1) / CHUNK; // 391 (<=512)

    size_t off = 0;
    auto carve = [&](size_t bytes) -> void* {
        void* p = (char*)d_ws + off;
        off += (bytes + 255) & ~(size_t)255;
        return p;
    };
    int*           histT    = (int*)carve((size_t)nbk * nchunks * 4);
    int*           tot      = (int*)carve((size_t)nbk * 4);
    unsigned*      bkt      = (unsigned*)carve((size_t)E * 4);
    int*           rowstart = (int*)carve((size_t)(N + 1) * 4);
    float*         dinv     = (float*)carve((size_t)N * 4);
    int*           adj      = (int*)carve((size_t)E * 4);
    unsigned char* h1       = (unsigned char*)carve((size_t)N * 128);   // fp8 e4m3
    __half*        z        = (__half*)carve((size_t)N * FDIM * 2);
    __half*        h2       = (__half*)h1;   // h1 dead after agg1; N x 40 fp16 fits

    hist_kernel<<<nchunks, 256, 0, stream>>>(ei + E, E, nchunks, nbk, histT);
    offsets_kernel<<<nbk, 512, 0, stream>>>(histT, nchunks, tot);
    scatter_kernel<<<nchunks, 256, 0, stream>>>(ei, E, nchunks, nbk, histT, tot, bkt);
    csr_kernel<<<nbk, 256, 0, stream>>>(tot, bkt, adj, rowstart, dinv, N, nbk, E);

    int nbt = (N + 127) / 128;
    gemm1_mfma<<<nbt, 256, 0, stream>>>(x, W1, h1, N);
    agg1_kernel<<<(N + 3) / 4, 256, 0, stream>>>(h1, rowstart, adj, dinv, x, b1, z, N);
    gemm2_mfma<<<nbt, 256, 0, stream>>>(z, W2, h2, N);
    agg2_kernel<<<(N + 3) / 4, 256, 0, stream>>>(h2, rowstart, adj, dinv, b2, y, N);
}